// Round 7
// baseline (60.532 us; speedup 1.0000x reference)
//
#include <hip/hip_runtime.h>

#define NTOK 16384
#define NC 2048
#define C4 512            // float4 per row
#define NE 8
#define TPB 256           // 4 waves
#define TOK_PER_WAVE 8
#define TOK_PER_BLOCK 32  // 4 waves x 8 tokens
#define NBLK (NTOK / TOK_PER_BLOCK)   // 512
#define NBANK 64          // aux-loss atomic banks

__global__ void zero_ws_kernel(float* ws) {
    const int tid = threadIdx.x;
    #pragma unroll
    for (int i = 0; i < 4; ++i) ws[tid + i * 256] = 0.0f;   // 1024 floats
}

// Scheme W: lane = (token t = lane>>3, phase phi = lane&7). Each lane keeps
// acc[8] (all experts, column subset phi::8). Live set ~65 VGPRs -> no spill
// (the R1-R5 disease). Gate traffic: 64KB per 8 tokens (4x less than R6).
// Reduce: shfl_xor 1/2/4 within the 8-lane phi group only.
__global__ __launch_bounds__(TPB, 2) void router_kernel(
    const float* __restrict__ x, const float* __restrict__ gw,
    float* __restrict__ out, float* __restrict__ ws) {
    __shared__ float s_psum[NE];
    __shared__ float s_cnt[NE];

    const int tid = threadIdx.x;
    if (tid < NE) { s_psum[tid] = 0.0f; s_cnt[tid] = 0.0f; }
    __syncthreads();

    const int wave = tid >> 6;
    const int lane = tid & 63;
    const int t    = lane >> 3;      // token within wave
    const int phi  = lane & 7;       // column phase
    const int token = blockIdx.x * TOK_PER_BLOCK + wave * TOK_PER_WAVE + t;

    const float4* xrow = (const float4*)x + (size_t)token * C4;
    const float4* gw4  = (const float4*)gw;

    float* out_w = out;               // weights [N,2]
    float* out_i = out + 2 * NTOK;    // indices [N,2] stored as float

    float acc[NE];
    #pragma unroll
    for (int e = 0; e < NE; ++e) acc[e] = 0.0f;

    #pragma unroll 2
    for (int step = 0; step < C4 / 8; ++step) {   // 64 iters
        const int c4 = step * 8 + phi;
        const float4 xv = xrow[c4];               // wave: 8 rows x 128B, coalesced
        #pragma unroll
        for (int e = 0; e < NE; ++e) {
            const float4 wv = gw4[e * C4 + c4];   // L1-resident
            acc[e] += xv.x * wv.x + xv.y * wv.y + xv.z * wv.z + xv.w * wv.w;
        }
    }

    // reduce over the 8 phases (masks 1,2,4 stay inside the phi group)
    #pragma unroll
    for (int m = 1; m < 8; m <<= 1)
        #pragma unroll
        for (int e = 0; e < NE; ++e)
            acc[e] += __shfl_xor(acc[e], m, 64);

    // every lane now has the token's full logits -> uniform epilogue
    float mx = acc[0];
    #pragma unroll
    for (int e = 1; e < NE; ++e) mx = fmaxf(mx, acc[e]);
    float p[NE];
    float s = 0.0f;
    #pragma unroll
    for (int e = 0; e < NE; ++e) { p[e] = expf(acc[e] - mx); s += p[e]; }
    const float inv = 1.0f / s;
    #pragma unroll
    for (int e = 0; e < NE; ++e) p[e] *= inv;

    // top-2, ties -> lower index (matches jax.lax.top_k)
    int i0 = 0; float p0 = p[0];
    #pragma unroll
    for (int e = 1; e < NE; ++e) if (p[e] > p0) { p0 = p[e]; i0 = e; }
    int i1 = (i0 == 0) ? 1 : 0; float p1 = p[i1];
    #pragma unroll
    for (int e = 0; e < NE; ++e)
        if (e != i0 && p[e] > p1) { p1 = p[e]; i1 = e; }

    if (phi == 0) {
        const float wsum = p0 + p1;
        out_w[2 * token]     = p0 / wsum;
        out_w[2 * token + 1] = p1 / wsum;
        out_i[2 * token]     = (float)i0;
        out_i[2 * token + 1] = (float)i1;
        atomicAdd(&s_cnt[i0], 1.0f);
    }
    if (phi == 1) atomicAdd(&s_cnt[i1], 1.0f);

    // p[phi] via static select chain (runtime-indexing a reg array -> scratch!)
    float pphi = p[0];
    pphi = (phi == 1) ? p[1] : pphi;
    pphi = (phi == 2) ? p[2] : pphi;
    pphi = (phi == 3) ? p[3] : pphi;
    pphi = (phi == 4) ? p[4] : pphi;
    pphi = (phi == 5) ? p[5] : pphi;
    pphi = (phi == 6) ? p[6] : pphi;
    pphi = (phi == 7) ? p[7] : pphi;
    atomicAdd(&s_psum[phi], pphi);   // one LDS atomic per lane, banked by phi

    __syncthreads();
    if (tid < NE) {
        const int bank = blockIdx.x & (NBANK - 1);
        atomicAdd(&ws[bank * 16 + tid], s_psum[tid]);
        atomicAdd(&ws[bank * 16 + NE + tid], s_cnt[tid]);
    }
}

__global__ void finalize_kernel(const float* __restrict__ ws,
                                float* __restrict__ out) {
    __shared__ float red[16];
    const int tid = threadIdx.x;   // 1024 threads = NBANK*16
    if (tid < 16) red[tid] = 0.0f;
    __syncthreads();
    atomicAdd(&red[tid & 15], ws[tid]);
    __syncthreads();
    if (tid == 0) {
        float aux = 0.0f;
        #pragma unroll
        for (int e = 0; e < NE; ++e)
            aux += (red[NE + e] * (1.0f / NTOK)) * (red[e] * (1.0f / NTOK));
        out[4 * NTOK] = (float)NE * aux;
    }
}

extern "C" void kernel_launch(void* const* d_in, const int* in_sizes, int n_in,
                              void* d_out, int out_size, void* d_ws, size_t ws_size,
                              hipStream_t stream) {
    const float* x  = (const float*)d_in[0];   // [4,4096,2048] f32
    const float* gw = (const float*)d_in[1];   // [8,2048] f32
    float* out = (float*)d_out;                // weights[N,2] | indices[N,2] | aux
    float* ws  = (float*)d_ws;                 // psum/cnt in 64 banks of 16

    zero_ws_kernel<<<1, 256, 0, stream>>>(ws);
    router_kernel<<<NBLK, TPB, 0, stream>>>(x, gw, out, ws);
    finalize_kernel<<<1, 1024, 0, stream>>>(ws, out);
}

// Round 8
// 43.977 us; speedup vs baseline: 1.3764x; 1.3764x over previous
//
#include <hip/hip_runtime.h>

#define NTOK 16384
#define NC 2048
#define C4 512            // float4 per row
#define NE 8
#define TPB 256           // 4 waves
#define TOKW 4            // tokens per wave
#define TOK_PER_BLOCK 16  // 4 waves x 4 tokens
#define NBLK (NTOK / TOK_PER_BLOCK)   // 1024

// Lore (R1-R7):
//  - __launch_bounds__(256,2) -> 128 VGPR cap; (.,4) -> 64 -> spill. Keep (256,2).
//  - acc as ONE 2D array spilled by compiler choice (R5, VGPR=48, 33MB scratch).
//    Separately-named acc0..acc3 arrays (R6 pattern) stay in regs.
//  - k-loop full unroll hoists all loads -> spill (R4). Keep #pragma unroll 2.
//  - Coalesced 1KB loads (idx = lane + k*64) are mandatory; per-lane divergent
//    gate addressing (R7 scheme) = 128B/instr + low occupancy -> regression.
__global__ __launch_bounds__(TPB, 2) void router_kernel(
    const float* __restrict__ x, const float* __restrict__ gw,
    float* __restrict__ out, float* __restrict__ ws) {
    __shared__ float s_psum[NE];
    __shared__ float s_cnt[NE];

    const int tid = threadIdx.x;
    if (tid < NE) { s_psum[tid] = 0.0f; s_cnt[tid] = 0.0f; }
    __syncthreads();

    const int wave = tid >> 6;
    const int lane = tid & 63;
    const float4* x4 = (const float4*)x;
    const float4* gw4 = (const float4*)gw;
    const int t0 = blockIdx.x * TOK_PER_BLOCK + wave * TOKW;

    float* out_w = out;               // weights [N,2]
    float* out_i = out + 2 * NTOK;    // indices [N,2] stored as float

    float acc0[NE], acc1[NE], acc2[NE], acc3[NE];
    #pragma unroll
    for (int e = 0; e < NE; ++e) { acc0[e] = 0.0f; acc1[e] = 0.0f; acc2[e] = 0.0f; acc3[e] = 0.0f; }

    #pragma unroll 2
    for (int k = 0; k < 8; ++k) {
        const int idx = lane + k * 64;
        const float4 xv0 = x4[(size_t)(t0 + 0) * C4 + idx];
        const float4 xv1 = x4[(size_t)(t0 + 1) * C4 + idx];
        const float4 xv2 = x4[(size_t)(t0 + 2) * C4 + idx];
        const float4 xv3 = x4[(size_t)(t0 + 3) * C4 + idx];
        #pragma unroll
        for (int e = 0; e < NE; ++e) {
            const float4 wv = gw4[e * C4 + idx];   // same addrs every block -> L1/L2
            acc0[e] += xv0.x * wv.x + xv0.y * wv.y + xv0.z * wv.z + xv0.w * wv.w;
            acc1[e] += xv1.x * wv.x + xv1.y * wv.y + xv1.z * wv.z + xv1.w * wv.w;
            acc2[e] += xv2.x * wv.x + xv2.y * wv.y + xv2.z * wv.z + xv2.w * wv.w;
            acc3[e] += xv3.x * wv.x + xv3.y * wv.y + xv3.z * wv.z + xv3.w * wv.w;
        }
    }

    // butterfly reduce over 64 lanes: every lane ends with full sums
    #pragma unroll
    for (int off = 32; off >= 1; off >>= 1) {
        #pragma unroll
        for (int e = 0; e < NE; ++e) {
            acc0[e] += __shfl_xor(acc0[e], off, 64);
            acc1[e] += __shfl_xor(acc1[e], off, 64);
            acc2[e] += __shfl_xor(acc2[e], off, 64);
            acc3[e] += __shfl_xor(acc3[e], off, 64);
        }
    }

    // every lane processes token (lane&3) -- static select chain, no runtime
    // indexing into register arrays (rule #20)
    const int t = lane & 3;
    float l[NE];
    #pragma unroll
    for (int e = 0; e < NE; ++e) {
        float v = acc0[e];
        v = (t == 1) ? acc1[e] : v;
        v = (t == 2) ? acc2[e] : v;
        v = (t == 3) ? acc3[e] : v;
        l[e] = v;
    }

    float mx = l[0];
    #pragma unroll
    for (int e = 1; e < NE; ++e) mx = fmaxf(mx, l[e]);
    float p[NE];
    float s = 0.0f;
    #pragma unroll
    for (int e = 0; e < NE; ++e) { p[e] = expf(l[e] - mx); s += p[e]; }
    const float inv = 1.0f / s;
    #pragma unroll
    for (int e = 0; e < NE; ++e) p[e] *= inv;

    // top-2, ties -> lower index (matches jax.lax.top_k)
    int i0 = 0; float p0 = p[0];
    #pragma unroll
    for (int e = 1; e < NE; ++e) if (p[e] > p0) { p0 = p[e]; i0 = e; }
    int i1 = (i0 == 0) ? 1 : 0; float p1 = p[i1];
    #pragma unroll
    for (int e = 0; e < NE; ++e)
        if (e != i0 && p[e] > p1) { p1 = p[e]; i1 = e; }

    if (lane < TOKW) {
        const int token = t0 + lane;
        const float wsum = p0 + p1;
        out_w[2 * token]     = p0 / wsum;
        out_w[2 * token + 1] = p1 / wsum;
        out_i[2 * token]     = (float)i0;
        out_i[2 * token + 1] = (float)i1;

        #pragma unroll
        for (int e = 0; e < NE; ++e) atomicAdd(&s_psum[e], p[e]);
        atomicAdd(&s_cnt[i0], 1.0f);
        atomicAdd(&s_cnt[i1], 1.0f);
    }

    __syncthreads();
    // non-atomic per-block partials -> no zero-init kernel needed
    if (tid < NE)          ws[blockIdx.x * 16 + tid] = s_psum[tid];
    else if (tid < 2 * NE) ws[blockIdx.x * 16 + tid] = s_cnt[tid - NE];
}

__global__ void finalize_kernel(const float* __restrict__ ws,
                                float* __restrict__ out) {
    __shared__ float red[16];
    const int tid = threadIdx.x;   // 1024 threads
    if (tid < 16) red[tid] = 0.0f;
    __syncthreads();
    // thread tid: entry i = tid&15, blocks b = tid>>4, stride 64 (coalesced)
    const int i = tid & 15;
    float sum = 0.0f;
    for (int b = (tid >> 4); b < NBLK; b += 64)
        sum += ws[b * 16 + i];
    atomicAdd(&red[i], sum);
    __syncthreads();
    if (tid == 0) {
        float aux = 0.0f;
        #pragma unroll
        for (int e = 0; e < NE; ++e)
            aux += (red[NE + e] * (1.0f / NTOK)) * (red[e] * (1.0f / NTOK));
        out[4 * NTOK] = (float)NE * aux;
    }
}

extern "C" void kernel_launch(void* const* d_in, const int* in_sizes, int n_in,
                              void* d_out, int out_size, void* d_ws, size_t ws_size,
                              hipStream_t stream) {
    const float* x  = (const float*)d_in[0];   // [4,4096,2048] f32
    const float* gw = (const float*)d_in[1];   // [8,2048] f32
    float* out = (float*)d_out;                // weights[N,2] | indices[N,2] | aux
    float* ws  = (float*)d_ws;                 // per-block partials [NBLK][16]

    router_kernel<<<NBLK, TPB, 0, stream>>>(x, gw, out, ws);
    finalize_kernel<<<1, 1024, 0, stream>>>(ws, out);
}